// Round 5
// baseline (128.227 us; speedup 1.0000x reference)
//
#include <hip/hip_runtime.h>

// Attention 8192x8192, D=DV=64, fp32 in/out.
// R5: R4 with 16 waves/block (1024 threads), grid 256 -> 4 waves/SIMD resident
// (was 2). Same per-wave structure: direct-from-global MFMA fragments
// (L2-resident bf16 K / V-transposed built by prepass), barrier-free K-loop,
// 32 rows/wave, 16-way key split, fixed-offset softmax, ones-MFMA row sums.

#define NQ 8192
#define NK 8192

typedef float f32x4 __attribute__((ext_vector_type(4)));
typedef short short8 __attribute__((ext_vector_type(8)));
union U4 { uint4 u; short8 s; };

#define MFMA16 __builtin_amdgcn_mfma_f32_16x16x32_bf16

// round-to-nearest-even fp32->bf16 pair pack (lo = a)
__device__ __forceinline__ unsigned pk2(float a, float b) {
    unsigned ua = __builtin_bit_cast(unsigned, a);
    unsigned ub = __builtin_bit_cast(unsigned, b);
    ua = (ua + 0x7FFFu + ((ua >> 16) & 1u)) >> 16;
    ub = (ub + 0x7FFFu + ((ub >> 16) & 1u)) & 0xFFFF0000u;
    return ua | ub;
}

// ---- prepass: K fp32 -> bf16 (same layout), V fp32 -> bf16 transposed ----
__global__ __launch_bounds__(256)
void prepass(const float* __restrict__ Kg, const float* __restrict__ Vg,
             unsigned short* __restrict__ Kb, unsigned short* __restrict__ Vt) {
    __shared__ float ld[64 * 33];
    const int t = threadIdx.x, b = blockIdx.x;

    {
        const int row = b * 32 + (t >> 3), dg = t & 7;
        const float* gp = Kg + (size_t)row * 64 + dg * 8;
        float4 f0 = *(const float4*)gp;
        float4 f1 = *(const float4*)(gp + 4);
        uint4 o = make_uint4(pk2(f0.x, f0.y), pk2(f0.z, f0.w),
                             pk2(f1.x, f1.y), pk2(f1.z, f1.w));
        *(uint4*)(Kb + (size_t)row * 64 + dg * 8) = o;
    }
    {
        const int key = t >> 3, dg = t & 7;
        const float* gp = Vg + (size_t)(b * 32 + key) * 64 + dg * 8;
        float4 f0 = *(const float4*)gp;
        float4 f1 = *(const float4*)(gp + 4);
        ld[(dg * 8 + 0) * 33 + key] = f0.x;
        ld[(dg * 8 + 1) * 33 + key] = f0.y;
        ld[(dg * 8 + 2) * 33 + key] = f0.z;
        ld[(dg * 8 + 3) * 33 + key] = f0.w;
        ld[(dg * 8 + 4) * 33 + key] = f1.x;
        ld[(dg * 8 + 5) * 33 + key] = f1.y;
        ld[(dg * 8 + 6) * 33 + key] = f1.z;
        ld[(dg * 8 + 7) * 33 + key] = f1.w;
    }
    __syncthreads();
    {
        const int dim = t >> 2, kq = t & 3;
        float v[8];
        #pragma unroll
        for (int j = 0; j < 8; ++j) v[j] = ld[dim * 33 + kq * 8 + j];
        uint4 o = make_uint4(pk2(v[0], v[1]), pk2(v[2], v[3]),
                             pk2(v[4], v[5]), pk2(v[6], v[7]));
        *(uint4*)(Vt + (size_t)dim * 8192 + b * 32 + kq * 8) = o;
    }
}

// ---- main kernel ----
__global__ __launch_bounds__(1024, 4)
void attn_main(const float* __restrict__ Qg,
               const unsigned short* __restrict__ Kb,
               const unsigned short* __restrict__ Vt,
               float* __restrict__ Og) {
    // LDS: 8 merge regions x 2080 floats (66,560 B); the first 2048 uint4
    // alias as the 32 P regions ([w][rt] x 64 uint4) during the main loop.
    __shared__ uint4 shb4[4160];
    float* sF = (float*)shb4;
    unsigned* shu = (unsigned*)shb4;

    const int t = threadIdx.x, w = t >> 6, lane = t & 63;
    const int q = lane >> 4, i16 = lane & 15;
    const int qb0 = blockIdx.x * 32;

    // Q fragments (scale 1/8 * log2 e folded)
    const float SCL = 0.18033688011112042f;
    short8 aq0, aq1, aq2, aq3;   // [rt][h]
    {
        const float* qp0 = Qg + (size_t)(qb0 + i16) * 64 + q * 8;
        const float* qp1 = Qg + (size_t)(qb0 + 16 + i16) * 64 + q * 8;
        U4 u;
        float4 f0, f1;
        f0 = *(const float4*)(qp0);      f1 = *(const float4*)(qp0 + 4);
        u.u = make_uint4(pk2(f0.x * SCL, f0.y * SCL), pk2(f0.z * SCL, f0.w * SCL),
                         pk2(f1.x * SCL, f1.y * SCL), pk2(f1.z * SCL, f1.w * SCL));
        aq0 = u.s;
        f0 = *(const float4*)(qp0 + 32); f1 = *(const float4*)(qp0 + 36);
        u.u = make_uint4(pk2(f0.x * SCL, f0.y * SCL), pk2(f0.z * SCL, f0.w * SCL),
                         pk2(f1.x * SCL, f1.y * SCL), pk2(f1.z * SCL, f1.w * SCL));
        aq1 = u.s;
        f0 = *(const float4*)(qp1);      f1 = *(const float4*)(qp1 + 4);
        u.u = make_uint4(pk2(f0.x * SCL, f0.y * SCL), pk2(f0.z * SCL, f0.w * SCL),
                         pk2(f1.x * SCL, f1.y * SCL), pk2(f1.z * SCL, f1.w * SCL));
        aq2 = u.s;
        f0 = *(const float4*)(qp1 + 32); f1 = *(const float4*)(qp1 + 36);
        u.u = make_uint4(pk2(f0.x * SCL, f0.y * SCL), pk2(f0.z * SCL, f0.w * SCL),
                         pk2(f1.x * SCL, f1.y * SCL), pk2(f1.z * SCL, f1.w * SCL));
        aq3 = u.s;
    }
    short8 bones;
    { U4 u; u.u = make_uint4(0x3F803F80u, 0x3F803F80u, 0x3F803F80u, 0x3F803F80u); bones = u.s; }

    f32x4 acc[2][4];   // static indices only
    f32x4 lacc[2];
    #pragma unroll
    for (int rt = 0; rt < 2; ++rt) {
        #pragma unroll
        for (int dt = 0; dt < 4; ++dt) { acc[rt][dt][0]=0.f; acc[rt][dt][1]=0.f; acc[rt][dt][2]=0.f; acc[rt][dt][3]=0.f; }
        lacc[rt][0]=0.f; lacc[rt][1]=0.f; lacc[rt][2]=0.f; lacc[rt][3]=0.f;
    }

    // P slot indices (layout verified in R2-R4)
    const int tpw = ((i16 >> 2) & 1) + 2 * q + 32 * (i16 >> 3);  // tp = tpw + 8r
    const int pp  = i16 & 3;
    const int tpr = (q & 1) + 2 * ((i16 >> 2) & 3) + 8 * (i16 & 3) + 32 * (q >> 1);

    uint4 kf0[4], vf0[4], kf1[4], vf1[4];

#define LOAD_TILE(TT, KD, VD)                                                        \
    do {                                                                             \
        const int kb_ = (TT) * 512;                                                  \
        _Pragma("unroll")                                                            \
        for (int e = 0; e < 2; ++e)                                                  \
            _Pragma("unroll")                                                        \
            for (int h = 0; h < 2; ++h)                                              \
                (KD)[e * 2 + h] = *(const uint4*)(Kb +                               \
                    ((size_t)(kb_ + w * 32 + 2 * i16 + e) << 6) + h * 32 + q * 8);   \
        _Pragma("unroll")                                                            \
        for (int dt = 0; dt < 4; ++dt)                                               \
            (VD)[dt] = *(const uint4*)(Vt + (size_t)(dt * 16 + i16) * 8192 +         \
                                       kb_ + w * 32 + q * 8);                        \
    } while (0)

#define COMPUTE(KD, VD)                                                              \
    do {                                                                             \
        f32x4 sfr[2][2];                                                             \
        _Pragma("unroll")                                                            \
        for (int rt = 0; rt < 2; ++rt)                                               \
            _Pragma("unroll")                                                        \
            for (int e = 0; e < 2; ++e) {                                            \
                f32x4 sacc;                                                          \
                sacc[0]=-16.f; sacc[1]=-16.f; sacc[2]=-16.f; sacc[3]=-16.f;          \
                U4 u0; u0.u = (KD)[e * 2 + 0];                                       \
                U4 u1; u1.u = (KD)[e * 2 + 1];                                       \
                sacc = MFMA16(rt ? aq2 : aq0, u0.s, sacc, 0, 0, 0);                  \
                sacc = MFMA16(rt ? aq3 : aq1, u1.s, sacc, 0, 0, 0);                  \
                sfr[rt][e] = sacc;                                                   \
            }                                                                        \
        _Pragma("unroll")                                                            \
        for (int rt = 0; rt < 2; ++rt) {                                             \
            const int rbase = (w * 2 + rt) * 256;                                    \
            _Pragma("unroll")                                                        \
            for (int r = 0; r < 4; ++r) {                                            \
                float p0 = __builtin_amdgcn_exp2f(sfr[rt][0][r]);                    \
                float p1 = __builtin_amdgcn_exp2f(sfr[rt][1][r]);                    \
                shu[rbase + (tpw + 8 * r) * 4 + pp] = pk2(p0, p1);                   \
            }                                                                        \
        }                                                                            \
        U4 ap0, ap1;                                                                 \
        ap0.u = shb4[(w * 2 + 0) * 64 + tpr];                                        \
        ap1.u = shb4[(w * 2 + 1) * 64 + tpr];                                        \
        lacc[0] = MFMA16(ap0.s, bones, lacc[0], 0, 0, 0);                            \
        lacc[1] = MFMA16(ap1.s, bones, lacc[1], 0, 0, 0);                            \
        _Pragma("unroll")                                                            \
        for (int dt = 0; dt < 4; ++dt) {                                             \
            U4 bv; bv.u = (VD)[dt];                                                  \
            acc[0][dt] = MFMA16(ap0.s, bv.s, acc[0][dt], 0, 0, 0);                   \
            acc[1][dt] = MFMA16(ap1.s, bv.s, acc[1][dt], 0, 0, 0);                   \
        }                                                                            \
    } while (0)

    LOAD_TILE(0, kf0, vf0);
    #pragma unroll 1
    for (int tt = 0; tt < 16; tt += 2) {
        LOAD_TILE(tt + 1, kf1, vf1);
        COMPUTE(kf0, vf0);
        LOAD_TILE((tt + 2) & 15, kf0, vf0);
        COMPUTE(kf1, vf1);
    }

    // ---- tree-merge the 16 key-split partials ----
    __syncthreads();
    for (int step = 8; step >= 1; step >>= 1) {
        if (w >= step && w < 2 * step) {
            float* base = sF + (w - step) * 2080;
            #pragma unroll
            for (int rt = 0; rt < 2; ++rt) {
                #pragma unroll
                for (int dt = 0; dt < 4; ++dt)
                    #pragma unroll
                    for (int r = 0; r < 4; ++r)
                        base[(rt * 16 + 4 * q + r) * 64 + dt * 16 + i16] = acc[rt][dt][r];
                if (i16 == 0) {
                    #pragma unroll
                    for (int r = 0; r < 4; ++r) base[2048 + rt * 16 + 4 * q + r] = lacc[rt][r];
                }
            }
        }
        __syncthreads();
        if (w < step) {
            const float* base = sF + w * 2080;
            #pragma unroll
            for (int rt = 0; rt < 2; ++rt) {
                #pragma unroll
                for (int dt = 0; dt < 4; ++dt)
                    #pragma unroll
                    for (int r = 0; r < 4; ++r)
                        acc[rt][dt][r] += base[(rt * 16 + 4 * q + r) * 64 + dt * 16 + i16];
                #pragma unroll
                for (int r = 0; r < 4; ++r) lacc[rt][r] += base[2048 + rt * 16 + 4 * q + r];
            }
        }
        __syncthreads();
    }

    // wave 0 normalizes into LDS; first 512 threads store float4
    if (w == 0) {
        #pragma unroll
        for (int rt = 0; rt < 2; ++rt)
            #pragma unroll
            for (int r = 0; r < 4; ++r) {
                const float inv = 1.0f / lacc[rt][r];
                #pragma unroll
                for (int dt = 0; dt < 4; ++dt)
                    sF[(rt * 16 + 4 * q + r) * 64 + dt * 16 + i16] = acc[rt][dt][r] * inv;
            }
    }
    __syncthreads();
    if (t < 512) {
        const int row = t >> 4, ds = t & 15;
        float4 o = *(const float4*)(sF + row * 64 + ds * 4);
        *(float4*)(Og + (size_t)(qb0 + row) * 64 + ds * 4) = o;
    }
}

extern "C" void kernel_launch(void* const* d_in, const int* in_sizes, int n_in,
                              void* d_out, int out_size, void* d_ws, size_t ws_size,
                              hipStream_t stream) {
    const float* Q = (const float*)d_in[0];
    const float* K = (const float*)d_in[1];
    const float* V = (const float*)d_in[2];
    float* O = (float*)d_out;
    unsigned short* Kb = (unsigned short*)d_ws;                       // 1 MB
    unsigned short* Vt = (unsigned short*)((char*)d_ws + (1 << 20));  // 1 MB
    hipLaunchKernelGGL(prepass, dim3(256), dim3(256), 0, stream, K, V, Kb, Vt);
    hipLaunchKernelGGL(attn_main, dim3(NQ / 32), dim3(1024), 0, stream, Q, Kb, Vt, O);
}

// Round 6
// 99.105 us; speedup vs baseline: 1.2938x; 1.2938x over previous
//
#include <hip/hip_runtime.h>

// Attention 8192x8192, D=DV=64, fp32 in/out.
// R6: R5 with the prepass writing Kb/Vt in wave-fragment-linear order so every
// main-loop fragment load is a fully-coalesced contiguous 1KB burst (SGPR base
// + lane-linear offset). Kills the 16-scattered-lines-per-instruction TCP
// serialization identified in R5. Compute structure unchanged: 16 waves/block,
// 32 Q-rows, 16-way key split, fixed-offset softmax, ones-MFMA row sums.

#define NQ 8192
#define NK 8192

typedef float f32x4 __attribute__((ext_vector_type(4)));
typedef short short8 __attribute__((ext_vector_type(8)));
union U4 { uint4 u; short8 s; };

#define MFMA16 __builtin_amdgcn_mfma_f32_16x16x32_bf16

// round-to-nearest-even fp32->bf16 pair pack (lo = a)
__device__ __forceinline__ unsigned pk2(float a, float b) {
    unsigned ua = __builtin_bit_cast(unsigned, a);
    unsigned ub = __builtin_bit_cast(unsigned, b);
    ua = (ua + 0x7FFFu + ((ua >> 16) & 1u)) >> 16;
    ub = (ub + 0x7FFFu + ((ub >> 16) & 1u)) & 0xFFFF0000u;
    return ua | ub;
}

// ---- prepass: swizzle K/V into fragment-linear bf16 layouts ----
// Kb4[(kc*4 + e*2 + h)*64 + i16*4 + q] = bf16x8 of K[kc*32 + 2*i16 + e][h*32+q*8 .. +8)
// Vt4[(kc*4 + dt)*64 + i16*4 + q]      = bf16x8 of V[kc*32 + q*8 .. +8)][dt*16+i16]
__global__ __launch_bounds__(256)
void prepass(const float* __restrict__ Kg, const float* __restrict__ Vg,
             uint4* __restrict__ Kb4, uint4* __restrict__ Vt4) {
    __shared__ float ld[64 * 33];
    const int t = threadIdx.x, b = blockIdx.x;   // b = key chunk (32 keys)

    // K: thread t covers key_local = t>>3 (0..31), dg = t&7 (h = dg>>2, q = dg&3)
    {
        const int kl = t >> 3, dg = t & 7;
        const int e = kl & 1, i16 = kl >> 1, h = dg >> 2, q = dg & 3;
        const float* gp = Kg + (size_t)(b * 32 + kl) * 64 + dg * 8;
        float4 f0 = *(const float4*)gp;
        float4 f1 = *(const float4*)(gp + 4);
        uint4 o = make_uint4(pk2(f0.x, f0.y), pk2(f0.z, f0.w),
                             pk2(f1.x, f1.y), pk2(f1.z, f1.w));
        Kb4[(size_t)(b * 4 + e * 2 + h) * 64 + i16 * 4 + q] = o;
    }
    // V transpose through LDS
    {
        const int key = t >> 3, dg = t & 7;
        const float* gp = Vg + (size_t)(b * 32 + key) * 64 + dg * 8;
        float4 f0 = *(const float4*)gp;
        float4 f1 = *(const float4*)(gp + 4);
        ld[(dg * 8 + 0) * 33 + key] = f0.x;
        ld[(dg * 8 + 1) * 33 + key] = f0.y;
        ld[(dg * 8 + 2) * 33 + key] = f0.z;
        ld[(dg * 8 + 3) * 33 + key] = f0.w;
        ld[(dg * 8 + 4) * 33 + key] = f1.x;
        ld[(dg * 8 + 5) * 33 + key] = f1.y;
        ld[(dg * 8 + 6) * 33 + key] = f1.z;
        ld[(dg * 8 + 7) * 33 + key] = f1.w;
    }
    __syncthreads();
    {
        const int dim = t >> 2, kq = t & 3;      // dim 0..63, kq = q (8-key group)
        const int dt = dim >> 4, i16 = dim & 15;
        float v[8];
        #pragma unroll
        for (int j = 0; j < 8; ++j) v[j] = ld[dim * 33 + kq * 8 + j];
        uint4 o = make_uint4(pk2(v[0], v[1]), pk2(v[2], v[3]),
                             pk2(v[4], v[5]), pk2(v[6], v[7]));
        Vt4[(size_t)(b * 4 + dt) * 64 + i16 * 4 + kq] = o;
    }
}

// ---- main kernel ----
__global__ __launch_bounds__(1024, 4)
void attn_main(const float* __restrict__ Qg,
               const uint4* __restrict__ Kb4,
               const uint4* __restrict__ Vt4,
               float* __restrict__ Og) {
    // LDS: 8 merge regions x 2080 floats (66,560 B); the first 2048 uint4
    // alias as the 32 P regions ([w][rt] x 64 uint4) during the main loop.
    __shared__ uint4 shb4[4160];
    float* sF = (float*)shb4;
    unsigned* shu = (unsigned*)shb4;

    const int t = threadIdx.x, w = t >> 6, lane = t & 63;
    const int q = lane >> 4, i16 = lane & 15;
    const int qb0 = blockIdx.x * 32;
    const int lsl = i16 * 4 + q;     // lane-linear slot within a 64-slot group

    // Q fragments (scale 1/8 * log2 e folded)
    const float SCL = 0.18033688011112042f;
    short8 aq0, aq1, aq2, aq3;   // [rt][h]
    {
        const float* qp0 = Qg + (size_t)(qb0 + i16) * 64 + q * 8;
        const float* qp1 = Qg + (size_t)(qb0 + 16 + i16) * 64 + q * 8;
        U4 u;
        float4 f0, f1;
        f0 = *(const float4*)(qp0);      f1 = *(const float4*)(qp0 + 4);
        u.u = make_uint4(pk2(f0.x * SCL, f0.y * SCL), pk2(f0.z * SCL, f0.w * SCL),
                         pk2(f1.x * SCL, f1.y * SCL), pk2(f1.z * SCL, f1.w * SCL));
        aq0 = u.s;
        f0 = *(const float4*)(qp0 + 32); f1 = *(const float4*)(qp0 + 36);
        u.u = make_uint4(pk2(f0.x * SCL, f0.y * SCL), pk2(f0.z * SCL, f0.w * SCL),
                         pk2(f1.x * SCL, f1.y * SCL), pk2(f1.z * SCL, f1.w * SCL));
        aq1 = u.s;
        f0 = *(const float4*)(qp1);      f1 = *(const float4*)(qp1 + 4);
        u.u = make_uint4(pk2(f0.x * SCL, f0.y * SCL), pk2(f0.z * SCL, f0.w * SCL),
                         pk2(f1.x * SCL, f1.y * SCL), pk2(f1.z * SCL, f1.w * SCL));
        aq2 = u.s;
        f0 = *(const float4*)(qp1 + 32); f1 = *(const float4*)(qp1 + 36);
        u.u = make_uint4(pk2(f0.x * SCL, f0.y * SCL), pk2(f0.z * SCL, f0.w * SCL),
                         pk2(f1.x * SCL, f1.y * SCL), pk2(f1.z * SCL, f1.w * SCL));
        aq3 = u.s;
    }
    short8 bones;
    { U4 u; u.u = make_uint4(0x3F803F80u, 0x3F803F80u, 0x3F803F80u, 0x3F803F80u); bones = u.s; }

    f32x4 acc[2][4];   // static indices only
    f32x4 lacc[2];
    #pragma unroll
    for (int rt = 0; rt < 2; ++rt) {
        #pragma unroll
        for (int dt = 0; dt < 4; ++dt) { acc[rt][dt][0]=0.f; acc[rt][dt][1]=0.f; acc[rt][dt][2]=0.f; acc[rt][dt][3]=0.f; }
        lacc[rt][0]=0.f; lacc[rt][1]=0.f; lacc[rt][2]=0.f; lacc[rt][3]=0.f;
    }

    // P slot indices (layout verified in R2-R5)
    const int tpw = ((i16 >> 2) & 1) + 2 * q + 32 * (i16 >> 3);  // tp = tpw + 8r
    const int pp  = i16 & 3;
    const int tpr = (q & 1) + 2 * ((i16 >> 2) & 3) + 8 * (i16 & 3) + 32 * (q >> 1);

    uint4 kf0[4], vf0[4], kf1[4], vf1[4];

    // chunk index for wave w in tile TT: kc = TT*16 + w; fragment-linear loads
#define LOAD_TILE(TT, KD, VD)                                                        \
    do {                                                                             \
        const size_t cb = ((size_t)(TT) * 16 + w) * 4;                               \
        _Pragma("unroll")                                                            \
        for (int eh = 0; eh < 4; ++eh)                                               \
            (KD)[eh] = Kb4[(cb + eh) * 64 + lsl];                                    \
        _Pragma("unroll")                                                            \
        for (int dt = 0; dt < 4; ++dt)                                               \
            (VD)[dt] = Vt4[(cb + dt) * 64 + lsl];                                    \
    } while (0)

#define COMPUTE(KD, VD)                                                              \
    do {                                                                             \
        f32x4 sfr[2][2];                                                             \
        _Pragma("unroll")                                                            \
        for (int rt = 0; rt < 2; ++rt)                                               \
            _Pragma("unroll")                                                        \
            for (int e = 0; e < 2; ++e) {                                            \
                f32x4 sacc;                                                          \
                sacc[0]=-16.f; sacc[1]=-16.f; sacc[2]=-16.f; sacc[3]=-16.f;          \
                U4 u0; u0.u = (KD)[e * 2 + 0];                                       \
                U4 u1; u1.u = (KD)[e * 2 + 1];                                       \
                sacc = MFMA16(rt ? aq2 : aq0, u0.s, sacc, 0, 0, 0);                  \
                sacc = MFMA16(rt ? aq3 : aq1, u1.s, sacc, 0, 0, 0);                  \
                sfr[rt][e] = sacc;                                                   \
            }                                                                        \
        _Pragma("unroll")                                                            \
        for (int rt = 0; rt < 2; ++rt) {                                             \
            const int rbase = (w * 2 + rt) * 256;                                    \
            _Pragma("unroll")                                                        \
            for (int r = 0; r < 4; ++r) {                                            \
                float p0 = __builtin_amdgcn_exp2f(sfr[rt][0][r]);                    \
                float p1 = __builtin_amdgcn_exp2f(sfr[rt][1][r]);                    \
                shu[rbase + (tpw + 8 * r) * 4 + pp] = pk2(p0, p1);                   \
            }                                                                        \
        }                                                                            \
        U4 ap0, ap1;                                                                 \
        ap0.u = shb4[(w * 2 + 0) * 64 + tpr];                                        \
        ap1.u = shb4[(w * 2 + 1) * 64 + tpr];                                        \
        lacc[0] = MFMA16(ap0.s, bones, lacc[0], 0, 0, 0);                            \
        lacc[1] = MFMA16(ap1.s, bones, lacc[1], 0, 0, 0);                            \
        _Pragma("unroll")                                                            \
        for (int dt = 0; dt < 4; ++dt) {                                             \
            U4 bv; bv.u = (VD)[dt];                                                  \
            acc[0][dt] = MFMA16(ap0.s, bv.s, acc[0][dt], 0, 0, 0);                   \
            acc[1][dt] = MFMA16(ap1.s, bv.s, acc[1][dt], 0, 0, 0);                   \
        }                                                                            \
    } while (0)

    LOAD_TILE(0, kf0, vf0);
    #pragma unroll 1
    for (int tt = 0; tt < 16; tt += 2) {
        LOAD_TILE(tt + 1, kf1, vf1);
        COMPUTE(kf0, vf0);
        LOAD_TILE((tt + 2) & 15, kf0, vf0);
        COMPUTE(kf1, vf1);
    }

    // ---- tree-merge the 16 key-split partials ----
    __syncthreads();
    for (int step = 8; step >= 1; step >>= 1) {
        if (w >= step && w < 2 * step) {
            float* base = sF + (w - step) * 2080;
            #pragma unroll
            for (int rt = 0; rt < 2; ++rt) {
                #pragma unroll
                for (int dt = 0; dt < 4; ++dt)
                    #pragma unroll
                    for (int r = 0; r < 4; ++r)
                        base[(rt * 16 + 4 * q + r) * 64 + dt * 16 + i16] = acc[rt][dt][r];
                if (i16 == 0) {
                    #pragma unroll
                    for (int r = 0; r < 4; ++r) base[2048 + rt * 16 + 4 * q + r] = lacc[rt][r];
                }
            }
        }
        __syncthreads();
        if (w < step) {
            const float* base = sF + w * 2080;
            #pragma unroll
            for (int rt = 0; rt < 2; ++rt) {
                #pragma unroll
                for (int dt = 0; dt < 4; ++dt)
                    #pragma unroll
                    for (int r = 0; r < 4; ++r)
                        acc[rt][dt][r] += base[(rt * 16 + 4 * q + r) * 64 + dt * 16 + i16];
                #pragma unroll
                for (int r = 0; r < 4; ++r) lacc[rt][r] += base[2048 + rt * 16 + 4 * q + r];
            }
        }
        __syncthreads();
    }

    // wave 0 normalizes into LDS; first 512 threads store float4
    if (w == 0) {
        #pragma unroll
        for (int rt = 0; rt < 2; ++rt)
            #pragma unroll
            for (int r = 0; r < 4; ++r) {
                const float inv = 1.0f / lacc[rt][r];
                #pragma unroll
                for (int dt = 0; dt < 4; ++dt)
                    sF[(rt * 16 + 4 * q + r) * 64 + dt * 16 + i16] = acc[rt][dt][r] * inv;
            }
    }
    __syncthreads();
    if (t < 512) {
        const int row = t >> 4, ds = t & 15;
        float4 o = *(const float4*)(sF + row * 64 + ds * 4);
        *(float4*)(Og + (size_t)(qb0 + row) * 64 + ds * 4) = o;
    }
}

extern "C" void kernel_launch(void* const* d_in, const int* in_sizes, int n_in,
                              void* d_out, int out_size, void* d_ws, size_t ws_size,
                              hipStream_t stream) {
    const float* Q = (const float*)d_in[0];
    const float* K = (const float*)d_in[1];
    const float* V = (const float*)d_in[2];
    float* O = (float*)d_out;
    uint4* Kb4 = (uint4*)d_ws;                        // 1 MB, fragment-linear
    uint4* Vt4 = (uint4*)((char*)d_ws + (1 << 20));   // 1 MB, fragment-linear
    hipLaunchKernelGGL(prepass, dim3(256), dim3(256), 0, stream, K, V, Kb4, Vt4);
    hipLaunchKernelGGL(attn_main, dim3(NQ / 32), dim3(1024), 0, stream, Q, Kb4, Vt4, O);
}